// Round 6
// baseline (359.118 us; speedup 1.0000x reference)
//
#include <hip/hip_runtime.h>
#include <stdint.h>
#include <stddef.h>

static constexpr int NB = 2;       // batch
static constexpr int SS = 2048;    // seq
static constexpr int DDim = 1024;  // model dim
static constexpr int NH = 16;      // heads
static constexpr size_t BSD = (size_t)NB * SS * DDim;  // 4194304
static constexpr size_t DDn = (size_t)DDim * DDim;     // 1048576

typedef __attribute__((ext_vector_type(4))) float f32x4;
typedef __attribute__((ext_vector_type(8))) short bf16x8;

// exp2-folded constants: softmax uses exp2f(logit*SCL2 + mask*MSK2)
static constexpr float SCL2 = 0.125f * 1.4426950408889634f;
static constexpr float MSK2 = -1.4426950408889634e9f;

__device__ __forceinline__ short f2bf(float f) {
  union { float f; unsigned u; } v; v.f = f;
  unsigned r = v.u + 0x7FFFu + ((v.u >> 16) & 1u);
  return (short)(r >> 16);
}

__device__ __forceinline__ void gload_lds16(const void* src, void* dst) {
  __builtin_amdgcn_global_load_lds(
      (const __attribute__((address_space(1))) void*)src,
      (__attribute__((address_space(3))) void*)dst, 16, 0, 0);
}

// ---------------- fp32 -> bf16 convert: 4 weight matrices, one launch ----------------
__global__ void cvtw_k(const float* __restrict__ w0, const float* __restrict__ w1,
                       const float* __restrict__ w2, const float* __restrict__ w3,
                       short* __restrict__ out) {
  int i = blockIdx.x * 256 + threadIdx.x;          // i in [0, 4*DDn/8)
  int mat = i >> 17;                               // DDn/8 = 2^17
  const float* src = mat == 0 ? w0 : mat == 1 ? w1 : mat == 2 ? w2 : w3;
  const f32x4* p = (const f32x4*)src + (size_t)(i & 131071) * 2;
  f32x4 a = p[0], c = p[1];
  bf16x8 o;
  o[0] = f2bf(a[0]); o[1] = f2bf(a[1]); o[2] = f2bf(a[2]); o[3] = f2bf(a[3]);
  o[4] = f2bf(c[0]); o[5] = f2bf(c[1]); o[6] = f2bf(c[2]); o[7] = f2bf(c[3]);
  ((bf16x8*)out)[i] = o;
}

// ---------------- fp32 -> bf16 convert: q,k,v, one launch ----------------
__global__ void cvt3_k(const float* __restrict__ t0, const float* __restrict__ t1,
                       const float* __restrict__ t2, short* __restrict__ out) {
  int i = blockIdx.x * 256 + threadIdx.x;          // i in [0, 3*BSD/8)
  int mat = i >> 19;                               // BSD/8 = 2^19
  const float* src = mat == 0 ? t0 : mat == 1 ? t1 : t2;
  const f32x4* p = (const f32x4*)src + (size_t)(i & 524287) * 2;
  f32x4 a = p[0], c = p[1];
  bf16x8 o;
  o[0] = f2bf(a[0]); o[1] = f2bf(a[1]); o[2] = f2bf(a[2]); o[3] = f2bf(a[3]);
  o[4] = f2bf(c[0]); o[5] = f2bf(c[1]); o[6] = f2bf(c[2]); o[7] = f2bf(c[3]);
  ((bf16x8*)out)[i] = o;
}

// ---------------- all-3 projections, one launch (R3/R5-proven dbuf GEMM body) ----------------
__global__ __launch_bounds__(256, 2) void proj3_k(
    const short* __restrict__ Acat, const short* __restrict__ Bcat,
    const float* __restrict__ bq, const float* __restrict__ bk, const float* __restrict__ bv,
    short* __restrict__ qh, short* __restrict__ kh, short* __restrict__ vhT) {
  __shared__ short la[2][4096], lb[2][4096];
  const int tid = threadIdx.x, wid = tid >> 6, lane = tid & 63;
  const int proj = blockIdx.z;
  const short* A = Acat + (size_t)proj * BSD;
  const short* Bm = Bcat + (size_t)proj * DDn;
  const float* bias = proj == 0 ? bq : proj == 1 ? bk : bv;
  const int bM = blockIdx.y * 128, bN = blockIdx.x * 128;
  const int ar = lane & 15, ak = (lane >> 4) * 8;
  const int srow = lane >> 2, scol = (lane & 3) * 8;
  const int wr = wid >> 1, wc = wid & 1;
  f32x4 acc[4][4];
#pragma unroll
  for (int m = 0; m < 4; ++m)
#pragma unroll
    for (int n = 0; n < 4; ++n) acc[m][n] = (f32x4){0.f, 0.f, 0.f, 0.f};

  auto stage = [&](int kt, int bb) {
    const int k0 = kt * 32;
#pragma unroll
    for (int c = 0; c < 2; ++c) {
      int chunk = c * 4 + wid;
      gload_lds16(A + (size_t)(bM + chunk * 16 + srow) * DDim + k0 + scol, &la[bb][chunk * 512]);
      gload_lds16(Bm + (size_t)(bN + chunk * 16 + srow) * DDim + k0 + scol, &lb[bb][chunk * 512]);
    }
  };

  stage(0, 0);
  asm volatile("s_waitcnt vmcnt(0)" ::: "memory");
  __syncthreads();
  for (int kt = 0; kt < 32; ++kt) {
    const int bb = kt & 1;
    if (kt < 31) stage(kt + 1, bb ^ 1);
    bf16x8 af[4], bfr[4];
#pragma unroll
    for (int m = 0; m < 4; ++m)
      af[m] = *(const bf16x8*)(&la[bb][(wr * 64 + m * 16 + ar) * 32 + ak]);
#pragma unroll
    for (int n = 0; n < 4; ++n)
      bfr[n] = *(const bf16x8*)(&lb[bb][(wc * 64 + n * 16 + ar) * 32 + ak]);
#pragma unroll
    for (int m = 0; m < 4; ++m)
#pragma unroll
      for (int n = 0; n < 4; ++n)
        acc[m][n] = __builtin_amdgcn_mfma_f32_16x16x32_bf16(af[m], bfr[n], acc[m][n], 0, 0, 0);
    asm volatile("s_waitcnt vmcnt(0)" ::: "memory");
    __syncthreads();
  }
#pragma unroll
  for (int m = 0; m < 4; ++m)
#pragma unroll
    for (int n = 0; n < 4; ++n)
#pragma unroll
      for (int r = 0; r < 4; ++r) {
        int gm = bM + wr * 64 + m * 16 + (lane >> 4) * 4 + r;
        int gn = bN + wc * 64 + n * 16 + (lane & 15);
        float val = acc[m][n][r] + bias[gn];
        int b = gm >> 11, s = gm & 2047, h = gn >> 6, d = gn & 63;
        if (proj == 2)
          vhT[(((size_t)b * NH + h) * 64 + d) * SS + s] = f2bf(val);
        else {
          short* o = proj == 0 ? qh : kh;
          o[(((size_t)b * NH + h) * SS + s) * 64 + d] = f2bf(val);
        }
      }
}

// ---------------- output projection (R3/R5-proven dbuf GEMM body, fp32 out) ----------------
__global__ __launch_bounds__(256, 2) void outproj_k(
    const short* __restrict__ A, const short* __restrict__ Bm,
    const float* __restrict__ bias, float* __restrict__ outp) {
  __shared__ short la[2][4096], lb[2][4096];
  const int tid = threadIdx.x, wid = tid >> 6, lane = tid & 63;
  const int bM = blockIdx.y * 128, bN = blockIdx.x * 128;
  const int ar = lane & 15, ak = (lane >> 4) * 8;
  const int srow = lane >> 2, scol = (lane & 3) * 8;
  const int wr = wid >> 1, wc = wid & 1;
  f32x4 acc[4][4];
#pragma unroll
  for (int m = 0; m < 4; ++m)
#pragma unroll
    for (int n = 0; n < 4; ++n) acc[m][n] = (f32x4){0.f, 0.f, 0.f, 0.f};

  auto stage = [&](int kt, int bb) {
    const int k0 = kt * 32;
#pragma unroll
    for (int c = 0; c < 2; ++c) {
      int chunk = c * 4 + wid;
      gload_lds16(A + (size_t)(bM + chunk * 16 + srow) * DDim + k0 + scol, &la[bb][chunk * 512]);
      gload_lds16(Bm + (size_t)(bN + chunk * 16 + srow) * DDim + k0 + scol, &lb[bb][chunk * 512]);
    }
  };

  stage(0, 0);
  asm volatile("s_waitcnt vmcnt(0)" ::: "memory");
  __syncthreads();
  for (int kt = 0; kt < 32; ++kt) {
    const int bb = kt & 1;
    if (kt < 31) stage(kt + 1, bb ^ 1);
    bf16x8 af[4], bfr[4];
#pragma unroll
    for (int m = 0; m < 4; ++m)
      af[m] = *(const bf16x8*)(&la[bb][(wr * 64 + m * 16 + ar) * 32 + ak]);
#pragma unroll
    for (int n = 0; n < 4; ++n)
      bfr[n] = *(const bf16x8*)(&lb[bb][(wc * 64 + n * 16 + ar) * 32 + ak]);
#pragma unroll
    for (int m = 0; m < 4; ++m)
#pragma unroll
      for (int n = 0; n < 4; ++n)
        acc[m][n] = __builtin_amdgcn_mfma_f32_16x16x32_bf16(af[m], bfr[n], acc[m][n], 0, 0, 0);
    asm volatile("s_waitcnt vmcnt(0)" ::: "memory");
    __syncthreads();
  }
#pragma unroll
  for (int m = 0; m < 4; ++m)
#pragma unroll
    for (int n = 0; n < 4; ++n)
#pragma unroll
      for (int r = 0; r < 4; ++r) {
        int gm = bM + wr * 64 + m * 16 + (lane >> 4) * 4 + r;
        int gn = bN + wc * 64 + n * 16 + (lane & 15);
        outp[(size_t)gm * DDim + gn] = acc[m][n][r] + bias[gn];
      }
}

// ---------------- fused attention: logits + softmax + W-write + PV ----------------
// One block = one (b,h) x one 128-row q-tile, 256 threads, 41KB LDS.
// K/V fragments are loaded DIRECTLY from global (no LDS staging): per head K+V =
// 512KB, L2-resident because grid.x=(b,h) pins each head's blocks to one XCD
// (linear id % 8 == bh % 8 -> 4 heads/XCD = 2MB < 4MiB L2).
// Sweep 1 (row sums) has ZERO barriers. Sweep 2 has only the two lP barriers,
// implemented as raw s_barrier + lgkmcnt(0)-only waits so the W global stores
// are never drained inside the loop (no per-tile vmcnt(0) stall).
__global__ __launch_bounds__(256, 2) void attn_k(
    const short* __restrict__ qh, const short* __restrict__ kh,
    const short* __restrict__ vhT, const float* __restrict__ mask,
    float* __restrict__ wout, short* __restrict__ concat) {
  __shared__ short lP[128 * 128];  // 32KB: Q staging, then P tile (bf16, swizzled)
  __shared__ float lmask[2048];    // 8KB
  __shared__ float lrs[2][128];    // 1KB
  const int tid = threadIdx.x, wid = tid >> 6, lane = tid & 63;
  const int wr = wid >> 1, wc = wid & 1;
  const int bh = blockIdx.x, b = bh >> 4, h = bh & 15;
  const int bM = blockIdx.y * 128;
  const short* Qb = qh + (size_t)bh * SS * 64 + (size_t)bM * 64;
  const short* Kb = kh + (size_t)bh * SS * 64;
  const short* Vb = vhT + (size_t)bh * 64 * SS;
  float* Wb = wout + (size_t)bh * SS * SS;

#pragma unroll
  for (int i = 0; i < 8; ++i)
    lmask[tid + i * 256] = mask[b * SS + tid + i * 256] * MSK2;

  // stage Q tile [128][64] swizzled into lP (one-time)
#pragma unroll
  for (int c = 0; c < 4; ++c) {
    int ob = c * 4096 + tid * 16;
    int row = ob >> 7, inrow = ob & 127;
    gload_lds16(Qb + row * 64 + ((inrow ^ ((row & 7) << 4)) >> 1), (char*)lP + ob);
  }
  asm volatile("s_waitcnt vmcnt(0)" ::: "memory");
  __syncthreads();
  bf16x8 af[4][2];
#pragma unroll
  for (int m = 0; m < 4; ++m)
#pragma unroll
    for (int kk = 0; kk < 2; ++kk) {
      int row = wr * 64 + m * 16 + (lane & 15);
      int kb = (kk * 32 + (lane >> 4) * 8) * 2;
      af[m][kk] = *(const bf16x8*)((const char*)lP + row * 128 + (kb ^ ((row & 7) << 4)));
    }

  // K/V fragment global addresses (per lane)
  const int krow = (lane & 15) * 64 + (lane >> 4) * 8;  // K row offset part + k-chunk
  // ---- sweep 1: row sums of exp2(logit*SCL2 + maskterm); no barriers ----
  float ps[4][4];
#pragma unroll
  for (int m = 0; m < 4; ++m)
#pragma unroll
    for (int r = 0; r < 4; ++r) ps[m][r] = 0.f;

  for (int kt = 0; kt < 16; ++kt) {
    bf16x8 bfr[4][2];
#pragma unroll
    for (int n = 0; n < 4; ++n)
#pragma unroll
      for (int kk = 0; kk < 2; ++kk)
        bfr[n][kk] = *(const bf16x8*)(Kb + (size_t)(kt * 128 + wc * 64 + n * 16) * 64 +
                                      krow + kk * 32);
#pragma unroll
    for (int n = 0; n < 4; ++n) {
      float mv = lmask[kt * 128 + wc * 64 + n * 16 + (lane & 15)];
#pragma unroll
      for (int m = 0; m < 4; ++m) {
        f32x4 a = (f32x4){0.f, 0.f, 0.f, 0.f};
        a = __builtin_amdgcn_mfma_f32_16x16x32_bf16(af[m][0], bfr[n][0], a, 0, 0, 0);
        a = __builtin_amdgcn_mfma_f32_16x16x32_bf16(af[m][1], bfr[n][1], a, 0, 0, 0);
#pragma unroll
        for (int r = 0; r < 4; ++r) ps[m][r] += exp2f(a[r] * SCL2 + mv);
      }
    }
  }
  // reduce over the 16 lanes holding one row's 16 cols
#pragma unroll
  for (int m = 0; m < 4; ++m)
#pragma unroll
    for (int r = 0; r < 4; ++r) {
      float s = ps[m][r];
      s += __shfl_xor(s, 1, 64);
      s += __shfl_xor(s, 2, 64);
      s += __shfl_xor(s, 4, 64);
      s += __shfl_xor(s, 8, 64);
      ps[m][r] = s;
    }
  if ((lane & 15) == 0) {
#pragma unroll
    for (int m = 0; m < 4; ++m)
#pragma unroll
      for (int r = 0; r < 4; ++r)
        lrs[wc][wr * 64 + m * 16 + (lane >> 4) * 4 + r] = ps[m][r];
  }
  __syncthreads();  // lrs visible; also guards lP reuse (af reads done long ago)
  float inv[4][4];
#pragma unroll
  for (int m = 0; m < 4; ++m)
#pragma unroll
    for (int r = 0; r < 4; ++r) {
      int row = wr * 64 + m * 16 + (lane >> 4) * 4 + r;
      inv[m][r] = 1.f / (lrs[0][row] + lrs[1][row]);
    }

  // ---- sweep 2: recompute logits, write weights, PV accumulate ----
  f32x4 pacc[4][2];
#pragma unroll
  for (int m = 0; m < 4; ++m)
#pragma unroll
    for (int n = 0; n < 2; ++n) pacc[m][n] = (f32x4){0.f, 0.f, 0.f, 0.f};

  for (int kt = 0; kt < 16; ++kt) {
    bf16x8 bfr[4][2];
#pragma unroll
    for (int n = 0; n < 4; ++n)
#pragma unroll
      for (int kk = 0; kk < 2; ++kk)
        bfr[n][kk] = *(const bf16x8*)(Kb + (size_t)(kt * 128 + wc * 64 + n * 16) * 64 +
                                      krow + kk * 32);
#pragma unroll
    for (int n = 0; n < 4; ++n) {
      int col = wc * 64 + n * 16 + (lane & 15);
      float mv = lmask[kt * 128 + col];
#pragma unroll
      for (int m = 0; m < 4; ++m) {
        f32x4 a = (f32x4){0.f, 0.f, 0.f, 0.f};
        a = __builtin_amdgcn_mfma_f32_16x16x32_bf16(af[m][0], bfr[n][0], a, 0, 0, 0);
        a = __builtin_amdgcn_mfma_f32_16x16x32_bf16(af[m][1], bfr[n][1], a, 0, 0, 0);
#pragma unroll
        for (int r = 0; r < 4; ++r) {
          int prow = wr * 64 + m * 16 + (lane >> 4) * 4 + r;
          float w = exp2f(a[r] * SCL2 + mv) * inv[m][r];
          Wb[(size_t)(bM + prow) * SS + kt * 128 + col] = w;  // store: never drained in-loop
          *(short*)((char*)lP + prow * 256 + ((col * 2) ^ ((prow & 7) << 4))) = f2bf(w);
        }
      }
    }
    // barrier 1: lP writes visible to all waves (LDS only -> lgkmcnt suffices)
    asm volatile("s_waitcnt lgkmcnt(0)" ::: "memory");
    __builtin_amdgcn_sched_barrier(0);
    __builtin_amdgcn_s_barrier();
    // PV: out[q][d] += P[q][k] * V^T[d][k]; V direct from global (L2-resident)
#pragma unroll
    for (int kk = 0; kk < 4; ++kk) {
      bf16x8 pa[4], bv[2];
      int kb = (kk * 32 + (lane >> 4) * 8) * 2;
#pragma unroll
      for (int m = 0; m < 4; ++m) {
        int row = wr * 64 + m * 16 + (lane & 15);
        pa[m] = *(const bf16x8*)((const char*)lP + row * 256 + (kb ^ ((row & 7) << 4)));
      }
#pragma unroll
      for (int n = 0; n < 2; ++n) {
        int d = wc * 32 + n * 16 + (lane & 15);
        bv[n] = *(const bf16x8*)(Vb + (size_t)d * SS + kt * 128 + kk * 32 + (lane >> 4) * 8);
      }
#pragma unroll
      for (int m = 0; m < 4; ++m)
#pragma unroll
        for (int n = 0; n < 2; ++n)
          pacc[m][n] = __builtin_amdgcn_mfma_f32_16x16x32_bf16(pa[m], bv[n], pacc[m][n], 0, 0, 0);
    }
    // barrier 2: all PV ds_reads of lP complete before next tile overwrites it
    asm volatile("s_waitcnt lgkmcnt(0)" ::: "memory");
    __builtin_amdgcn_sched_barrier(0);
    __builtin_amdgcn_s_barrier();
  }
  // epilogue: attn (concat layout) bf16
#pragma unroll
  for (int m = 0; m < 4; ++m)
#pragma unroll
    for (int n = 0; n < 2; ++n)
#pragma unroll
      for (int r = 0; r < 4; ++r) {
        int s = bM + wr * 64 + m * 16 + (lane >> 4) * 4 + r;
        int d = wc * 32 + n * 16 + (lane & 15);
        concat[((size_t)(b * SS + s)) * DDim + h * 64 + d] = f2bf(pacc[m][n][r]);
      }
}

extern "C" void kernel_launch(void* const* d_in, const int* in_sizes, int n_in,
                              void* d_out, int out_size, void* d_ws, size_t ws_size,
                              hipStream_t stream) {
  const float* q = (const float*)d_in[0];
  const float* k = (const float*)d_in[1];
  const float* v = (const float*)d_in[2];
  const float* mask = (const float*)d_in[3];
  const float* wq_w = (const float*)d_in[4];
  const float* wq_b = (const float*)d_in[5];
  const float* wk_w = (const float*)d_in[6];
  const float* wk_b = (const float*)d_in[7];
  const float* wv_w = (const float*)d_in[8];
  const float* wv_b = (const float*)d_in[9];
  const float* wo_w = (const float*)d_in[10];
  const float* wo_b = (const float*)d_in[11];

  // ws layout (shorts)
  short* qb = (short*)d_ws;       // qb,kb,vb contiguous (Acat): 3*BSD
  short* wqb = qb + 3 * BSD;      // wq,wk,wv contiguous (Bcat): 3*DDn
  short* wob = wqb + 3 * DDn;     // DDn
  short* qh = wob + DDn;
  short* kh = qh + BSD;
  short* vhT = kh + BSD;
  short* concat = vhT + BSD;

  float* out0 = (float*)d_out;
  float* wts = out0 + BSD;  // [B,H,S,S] fp32

  cvtw_k<<<2048, 256, 0, stream>>>(wq_w, wk_w, wv_w, wo_w, wqb);
  cvt3_k<<<6144, 256, 0, stream>>>(q, k, v, qb);

  dim3 gproj(DDim / 128, (NB * SS) / 128, 3);  // (8, 32, 3)
  proj3_k<<<gproj, 256, 0, stream>>>(qb, wqb, wq_b, wk_b, wv_b, qh, kh, vhT);

  dim3 gattn(NB * NH, SS / 128);  // (32, 16): x=(b,h) pins each head to one XCD
  attn_k<<<gattn, 256, 0, stream>>>(qh, kh, vhT, mask, wts, concat);

  dim3 gout(DDim / 128, (NB * SS) / 128);  // (8, 32)
  outproj_k<<<gout, 256, 0, stream>>>(concat, wob, wo_b, out0);
}

// Round 7
// 332.046 us; speedup vs baseline: 1.0815x; 1.0815x over previous
//
#include <hip/hip_runtime.h>
#include <stdint.h>
#include <stddef.h>

static constexpr int NB = 2;       // batch
static constexpr int SS = 2048;    // seq
static constexpr int DDim = 1024;  // model dim
static constexpr int NH = 16;      // heads
static constexpr size_t BSD = (size_t)NB * SS * DDim;  // 4194304
static constexpr size_t DDn = (size_t)DDim * DDim;     // 1048576

typedef __attribute__((ext_vector_type(4))) float f32x4;
typedef __attribute__((ext_vector_type(8))) short bf16x8;
typedef __attribute__((ext_vector_type(4))) short bf16x4;

// exp2-folded constants: softmax uses exp2f(logit*SCL2 + mask*MSK2)
static constexpr float SCL2 = 0.125f * 1.4426950408889634f;
static constexpr float MSK2 = -1.4426950408889634e9f;

__device__ __forceinline__ short f2bf(float f) {
  union { float f; unsigned u; } v; v.f = f;
  unsigned r = v.u + 0x7FFFu + ((v.u >> 16) & 1u);
  return (short)(r >> 16);
}

__device__ __forceinline__ void gload_lds16(const void* src, void* dst) {
  __builtin_amdgcn_global_load_lds(
      (const __attribute__((address_space(1))) void*)src,
      (__attribute__((address_space(3))) void*)dst, 16, 0, 0);
}

// ---------------- fp32 -> bf16 convert: 4 weight matrices, one launch ----------------
__global__ void cvtw_k(const float* __restrict__ w0, const float* __restrict__ w1,
                       const float* __restrict__ w2, const float* __restrict__ w3,
                       short* __restrict__ out) {
  int i = blockIdx.x * 256 + threadIdx.x;          // i in [0, 4*DDn/8)
  int mat = i >> 17;                               // DDn/8 = 2^17
  const float* src = mat == 0 ? w0 : mat == 1 ? w1 : mat == 2 ? w2 : w3;
  const f32x4* p = (const f32x4*)src + (size_t)(i & 131071) * 2;
  f32x4 a = p[0], c = p[1];
  bf16x8 o;
  o[0] = f2bf(a[0]); o[1] = f2bf(a[1]); o[2] = f2bf(a[2]); o[3] = f2bf(a[3]);
  o[4] = f2bf(c[0]); o[5] = f2bf(c[1]); o[6] = f2bf(c[2]); o[7] = f2bf(c[3]);
  ((bf16x8*)out)[i] = o;
}

// ---------------- fp32 -> bf16 convert: q,k,v, one launch ----------------
__global__ void cvt3_k(const float* __restrict__ t0, const float* __restrict__ t1,
                       const float* __restrict__ t2, short* __restrict__ out) {
  int i = blockIdx.x * 256 + threadIdx.x;          // i in [0, 3*BSD/8)
  int mat = i >> 19;                               // BSD/8 = 2^19
  const float* src = mat == 0 ? t0 : mat == 1 ? t1 : t2;
  const f32x4* p = (const f32x4*)src + (size_t)(i & 524287) * 2;
  f32x4 a = p[0], c = p[1];
  bf16x8 o;
  o[0] = f2bf(a[0]); o[1] = f2bf(a[1]); o[2] = f2bf(a[2]); o[3] = f2bf(a[3]);
  o[4] = f2bf(c[0]); o[5] = f2bf(c[1]); o[6] = f2bf(c[2]); o[7] = f2bf(c[3]);
  ((bf16x8*)out)[i] = o;
}

// ---------------- all-3 projections, one launch (R3/R5-proven dbuf GEMM body) ----------------
__global__ __launch_bounds__(256, 2) void proj3_k(
    const short* __restrict__ Acat, const short* __restrict__ Bcat,
    const float* __restrict__ bq, const float* __restrict__ bk, const float* __restrict__ bv,
    short* __restrict__ qh, short* __restrict__ kh, short* __restrict__ vhT) {
  __shared__ short la[2][4096], lb[2][4096];
  const int tid = threadIdx.x, wid = tid >> 6, lane = tid & 63;
  const int proj = blockIdx.z;
  const short* A = Acat + (size_t)proj * BSD;
  const short* Bm = Bcat + (size_t)proj * DDn;
  const float* bias = proj == 0 ? bq : proj == 1 ? bk : bv;
  const int bM = blockIdx.y * 128, bN = blockIdx.x * 128;
  const int ar = lane & 15, ak = (lane >> 4) * 8;
  const int srow = lane >> 2, scol = (lane & 3) * 8;
  const int wr = wid >> 1, wc = wid & 1;
  f32x4 acc[4][4];
#pragma unroll
  for (int m = 0; m < 4; ++m)
#pragma unroll
    for (int n = 0; n < 4; ++n) acc[m][n] = (f32x4){0.f, 0.f, 0.f, 0.f};

  auto stage = [&](int kt, int bb) {
    const int k0 = kt * 32;
#pragma unroll
    for (int c = 0; c < 2; ++c) {
      int chunk = c * 4 + wid;
      gload_lds16(A + (size_t)(bM + chunk * 16 + srow) * DDim + k0 + scol, &la[bb][chunk * 512]);
      gload_lds16(Bm + (size_t)(bN + chunk * 16 + srow) * DDim + k0 + scol, &lb[bb][chunk * 512]);
    }
  };

  stage(0, 0);
  asm volatile("s_waitcnt vmcnt(0)" ::: "memory");
  __syncthreads();
  for (int kt = 0; kt < 32; ++kt) {
    const int bb = kt & 1;
    if (kt < 31) stage(kt + 1, bb ^ 1);
    bf16x8 af[4], bfr[4];
#pragma unroll
    for (int m = 0; m < 4; ++m)
      af[m] = *(const bf16x8*)(&la[bb][(wr * 64 + m * 16 + ar) * 32 + ak]);
#pragma unroll
    for (int n = 0; n < 4; ++n)
      bfr[n] = *(const bf16x8*)(&lb[bb][(wc * 64 + n * 16 + ar) * 32 + ak]);
#pragma unroll
    for (int m = 0; m < 4; ++m)
#pragma unroll
      for (int n = 0; n < 4; ++n)
        acc[m][n] = __builtin_amdgcn_mfma_f32_16x16x32_bf16(af[m], bfr[n], acc[m][n], 0, 0, 0);
    asm volatile("s_waitcnt vmcnt(0)" ::: "memory");
    __syncthreads();
  }
#pragma unroll
  for (int m = 0; m < 4; ++m)
#pragma unroll
    for (int n = 0; n < 4; ++n)
#pragma unroll
      for (int r = 0; r < 4; ++r) {
        int gm = bM + wr * 64 + m * 16 + (lane >> 4) * 4 + r;
        int gn = bN + wc * 64 + n * 16 + (lane & 15);
        float val = acc[m][n][r] + bias[gn];
        int b = gm >> 11, s = gm & 2047, h = gn >> 6, d = gn & 63;
        if (proj == 2)
          vhT[(((size_t)b * NH + h) * 64 + d) * SS + s] = f2bf(val);
        else {
          short* o = proj == 0 ? qh : kh;
          o[(((size_t)b * NH + h) * SS + s) * 64 + d] = f2bf(val);
        }
      }
}

// ---------------- output projection (R3/R5-proven dbuf GEMM body, fp32 out) ----------------
__global__ __launch_bounds__(256, 2) void outproj_k(
    const short* __restrict__ A, const short* __restrict__ Bm,
    const float* __restrict__ bias, float* __restrict__ outp) {
  __shared__ short la[2][4096], lb[2][4096];
  const int tid = threadIdx.x, wid = tid >> 6, lane = tid & 63;
  const int bM = blockIdx.y * 128, bN = blockIdx.x * 128;
  const int ar = lane & 15, ak = (lane >> 4) * 8;
  const int srow = lane >> 2, scol = (lane & 3) * 8;
  const int wr = wid >> 1, wc = wid & 1;
  f32x4 acc[4][4];
#pragma unroll
  for (int m = 0; m < 4; ++m)
#pragma unroll
    for (int n = 0; n < 4; ++n) acc[m][n] = (f32x4){0.f, 0.f, 0.f, 0.f};

  auto stage = [&](int kt, int bb) {
    const int k0 = kt * 32;
#pragma unroll
    for (int c = 0; c < 2; ++c) {
      int chunk = c * 4 + wid;
      gload_lds16(A + (size_t)(bM + chunk * 16 + srow) * DDim + k0 + scol, &la[bb][chunk * 512]);
      gload_lds16(Bm + (size_t)(bN + chunk * 16 + srow) * DDim + k0 + scol, &lb[bb][chunk * 512]);
    }
  };

  stage(0, 0);
  asm volatile("s_waitcnt vmcnt(0)" ::: "memory");
  __syncthreads();
  for (int kt = 0; kt < 32; ++kt) {
    const int bb = kt & 1;
    if (kt < 31) stage(kt + 1, bb ^ 1);
    bf16x8 af[4], bfr[4];
#pragma unroll
    for (int m = 0; m < 4; ++m)
      af[m] = *(const bf16x8*)(&la[bb][(wr * 64 + m * 16 + ar) * 32 + ak]);
#pragma unroll
    for (int n = 0; n < 4; ++n)
      bfr[n] = *(const bf16x8*)(&lb[bb][(wc * 64 + n * 16 + ar) * 32 + ak]);
#pragma unroll
    for (int m = 0; m < 4; ++m)
#pragma unroll
      for (int n = 0; n < 4; ++n)
        acc[m][n] = __builtin_amdgcn_mfma_f32_16x16x32_bf16(af[m], bfr[n], acc[m][n], 0, 0, 0);
    asm volatile("s_waitcnt vmcnt(0)" ::: "memory");
    __syncthreads();
  }
#pragma unroll
  for (int m = 0; m < 4; ++m)
#pragma unroll
    for (int n = 0; n < 4; ++n)
#pragma unroll
      for (int r = 0; r < 4; ++r) {
        int gm = bM + wr * 64 + m * 16 + (lane >> 4) * 4 + r;
        int gn = bN + wc * 64 + n * 16 + (lane & 15);
        outp[(size_t)gm * DDim + gn] = acc[m][n][r] + bias[gn];
      }
}

// ---------------- fused attention (R5-proven skeleton, swapped-QK^T output) ----------------
// One block = one (b,h) x one 128-row q-tile, 256 threads, ~73KB LDS -> 2 blocks/CU.
// QK^T computed as mfma(K_frag, Q_frag) so each lane's f32x4 holds 4 CONSECUTIVE k
// for one q row (q=lane&15): W-stores become dwordx4 (nontemporal), P LDS writes
// become ds_write_b64, row-reduce is 2 shuffles. Staging/barriers identical to R5.
__global__ __launch_bounds__(256, 2) void attn_k(
    const short* __restrict__ qh, const short* __restrict__ kh,
    const short* __restrict__ vhT, const float* __restrict__ mask,
    float* __restrict__ wout, short* __restrict__ concat) {
  __shared__ short lP[128 * 128];  // Q staging, then P tile (bf16, swizzled)
  __shared__ short lK[128 * 64];   // K tile (swizzled)
  __shared__ short lV[64 * 128];   // V^T tile (swizzled)
  __shared__ float lmask[2048];
  __shared__ float lrs[2][128];
  const int tid = threadIdx.x, wid = tid >> 6, lane = tid & 63;
  const int wr = wid >> 1, wc = wid & 1;
  const int bh = blockIdx.y, b = bh >> 4, h = bh & 15;
  const int bM = blockIdx.x * 128;
  const short* Qb = qh + (size_t)bh * SS * 64 + (size_t)bM * 64;
  const short* Kb = kh + (size_t)bh * SS * 64;
  const short* Vb = vhT + (size_t)bh * 64 * SS;
  float* Wb = wout + (size_t)bh * SS * SS;

#pragma unroll
  for (int i = 0; i < 8; ++i)
    lmask[tid + i * 256] = mask[b * SS + tid + i * 256] * MSK2;

  // stage Q tile [128][64] swizzled into lP
#pragma unroll
  for (int c = 0; c < 4; ++c) {
    int ob = c * 4096 + tid * 16;
    int row = ob >> 7, inrow = ob & 127;
    gload_lds16(Qb + row * 64 + ((inrow ^ ((row & 7) << 4)) >> 1), (char*)lP + ob);
  }
  asm volatile("s_waitcnt vmcnt(0)" ::: "memory");
  __syncthreads();
  bf16x8 af[4][2];  // Q fragments: rows wr*64+nq*16+(lane&15)
#pragma unroll
  for (int m = 0; m < 4; ++m)
#pragma unroll
    for (int kk = 0; kk < 2; ++kk) {
      int row = wr * 64 + m * 16 + (lane & 15);
      int kb = (kk * 32 + (lane >> 4) * 8) * 2;
      af[m][kk] = *(const bf16x8*)((const char*)lP + row * 128 + (kb ^ ((row & 7) << 4)));
    }

  // ---- sweep 1: row sums of exp2(logit*SCL2 + maskterm) ----
  float ps[4];  // per nq (q = wr*64 + nq*16 + (lane&15))
#pragma unroll
  for (int n = 0; n < 4; ++n) ps[n] = 0.f;

  for (int kt = 0; kt < 16; ++kt) {
    __syncthreads();
#pragma unroll
    for (int c = 0; c < 4; ++c) {
      int ob = c * 4096 + tid * 16;
      int row = ob >> 7, inrow = ob & 127;
      gload_lds16(Kb + (size_t)(kt * 128 + row) * 64 + ((inrow ^ ((row & 7) << 4)) >> 1),
                  (char*)lK + ob);
    }
    asm volatile("s_waitcnt vmcnt(0)" ::: "memory");
    __syncthreads();
    bf16x8 bfr[4][2];  // K fragments: rows wc*64+mk*16+(lane&15)
#pragma unroll
    for (int mk = 0; mk < 4; ++mk)
#pragma unroll
      for (int kk = 0; kk < 2; ++kk) {
        int row = wc * 64 + mk * 16 + (lane & 15);
        int kb = (kk * 32 + (lane >> 4) * 8) * 2;
        bfr[mk][kk] = *(const bf16x8*)((const char*)lK + row * 128 + (kb ^ ((row & 7) << 4)));
      }
#pragma unroll
    for (int mk = 0; mk < 4; ++mk) {
      f32x4 mv4 = *(const f32x4*)&lmask[kt * 128 + wc * 64 + mk * 16 + (lane >> 4) * 4];
#pragma unroll
      for (int nq = 0; nq < 4; ++nq) {
        f32x4 a = (f32x4){0.f, 0.f, 0.f, 0.f};
        a = __builtin_amdgcn_mfma_f32_16x16x32_bf16(bfr[mk][0], af[nq][0], a, 0, 0, 0);
        a = __builtin_amdgcn_mfma_f32_16x16x32_bf16(bfr[mk][1], af[nq][1], a, 0, 0, 0);
#pragma unroll
        for (int r = 0; r < 4; ++r) ps[nq] += exp2f(a[r] * SCL2 + mv4[r]);
      }
    }
  }
  // reduce across the 4 lane-groups (lane>>4) holding one q's k-chunks
#pragma unroll
  for (int n = 0; n < 4; ++n) {
    float s = ps[n];
    s += __shfl_xor(s, 16, 64);
    s += __shfl_xor(s, 32, 64);
    ps[n] = s;
  }
  if (lane < 16) {
#pragma unroll
    for (int n = 0; n < 4; ++n) lrs[wc][wr * 64 + n * 16 + lane] = ps[n];
  }
  __syncthreads();
  float inv[4];
#pragma unroll
  for (int n = 0; n < 4; ++n) {
    int row = wr * 64 + n * 16 + (lane & 15);
    inv[n] = 1.f / (lrs[0][row] + lrs[1][row]);
  }

  // ---- sweep 2: recompute logits, write weights (x4), PV accumulate ----
  f32x4 pacc[4][2];
#pragma unroll
  for (int m = 0; m < 4; ++m)
#pragma unroll
    for (int n = 0; n < 2; ++n) pacc[m][n] = (f32x4){0.f, 0.f, 0.f, 0.f};

  for (int kt = 0; kt < 16; ++kt) {
    __syncthreads();
#pragma unroll
    for (int c = 0; c < 4; ++c) {
      int ob = c * 4096 + tid * 16;
      int row = ob >> 7, inrow = ob & 127;
      gload_lds16(Kb + (size_t)(kt * 128 + row) * 64 + ((inrow ^ ((row & 7) << 4)) >> 1),
                  (char*)lK + ob);
    }
#pragma unroll
    for (int c = 0; c < 4; ++c) {
      int ob = c * 4096 + tid * 16;
      int row = ob >> 8, inrow = ob & 255;
      gload_lds16(Vb + (size_t)row * SS + kt * 128 + ((inrow ^ ((row & 7) << 4)) >> 1),
                  (char*)lV + ob);
    }
    asm volatile("s_waitcnt vmcnt(0)" ::: "memory");
    __syncthreads();
    bf16x8 bfr[4][2];
#pragma unroll
    for (int mk = 0; mk < 4; ++mk)
#pragma unroll
      for (int kk = 0; kk < 2; ++kk) {
        int row = wc * 64 + mk * 16 + (lane & 15);
        int kb = (kk * 32 + (lane >> 4) * 8) * 2;
        bfr[mk][kk] = *(const bf16x8*)((const char*)lK + row * 128 + (kb ^ ((row & 7) << 4)));
      }
#pragma unroll
    for (int mk = 0; mk < 4; ++mk) {
      const int klocal = wc * 64 + mk * 16 + (lane >> 4) * 4;
      f32x4 mv4 = *(const f32x4*)&lmask[kt * 128 + klocal];
#pragma unroll
      for (int nq = 0; nq < 4; ++nq) {
        f32x4 a = (f32x4){0.f, 0.f, 0.f, 0.f};
        a = __builtin_amdgcn_mfma_f32_16x16x32_bf16(bfr[mk][0], af[nq][0], a, 0, 0, 0);
        a = __builtin_amdgcn_mfma_f32_16x16x32_bf16(bfr[mk][1], af[nq][1], a, 0, 0, 0);
        const int qrow = wr * 64 + nq * 16 + (lane & 15);
        f32x4 w4;
#pragma unroll
        for (int r = 0; r < 4; ++r) w4[r] = exp2f(a[r] * SCL2 + mv4[r]) * inv[nq];
        __builtin_nontemporal_store(
            w4, (f32x4*)&Wb[(size_t)(bM + qrow) * SS + kt * 128 + klocal]);
        bf16x4 p4;
        p4[0] = f2bf(w4[0]); p4[1] = f2bf(w4[1]); p4[2] = f2bf(w4[2]); p4[3] = f2bf(w4[3]);
        *(bf16x4*)((char*)lP + qrow * 256 + ((klocal * 2) ^ ((qrow & 7) << 4))) = p4;
      }
    }
    __syncthreads();  // lP ready
    // PV: out[q][d] += P[q][k] * V^T[d][k]
#pragma unroll
    for (int kk = 0; kk < 4; ++kk) {
      bf16x8 pa[4], bv[2];
      int kb = (kk * 32 + (lane >> 4) * 8) * 2;
#pragma unroll
      for (int m = 0; m < 4; ++m) {
        int row = wr * 64 + m * 16 + (lane & 15);
        pa[m] = *(const bf16x8*)((const char*)lP + row * 256 + (kb ^ ((row & 7) << 4)));
      }
#pragma unroll
      for (int n = 0; n < 2; ++n) {
        int d = wc * 32 + n * 16 + (lane & 15);
        bv[n] = *(const bf16x8*)((const char*)lV + d * 256 + (kb ^ ((d & 7) << 4)));
      }
#pragma unroll
      for (int m = 0; m < 4; ++m)
#pragma unroll
        for (int n = 0; n < 2; ++n)
          pacc[m][n] = __builtin_amdgcn_mfma_f32_16x16x32_bf16(pa[m], bv[n], pacc[m][n], 0, 0, 0);
    }
  }
  // epilogue: attn (concat layout) bf16
#pragma unroll
  for (int m = 0; m < 4; ++m)
#pragma unroll
    for (int n = 0; n < 2; ++n)
#pragma unroll
      for (int r = 0; r < 4; ++r) {
        int s = bM + wr * 64 + m * 16 + (lane >> 4) * 4 + r;
        int d = wc * 32 + n * 16 + (lane & 15);
        concat[((size_t)(b * SS + s)) * DDim + h * 64 + d] = f2bf(pacc[m][n][r]);
      }
}

extern "C" void kernel_launch(void* const* d_in, const int* in_sizes, int n_in,
                              void* d_out, int out_size, void* d_ws, size_t ws_size,
                              hipStream_t stream) {
  const float* q = (const float*)d_in[0];
  const float* k = (const float*)d_in[1];
  const float* v = (const float*)d_in[2];
  const float* mask = (const float*)d_in[3];
  const float* wq_w = (const float*)d_in[4];
  const float* wq_b = (const float*)d_in[5];
  const float* wk_w = (const float*)d_in[6];
  const float* wk_b = (const float*)d_in[7];
  const float* wv_w = (const float*)d_in[8];
  const float* wv_b = (const float*)d_in[9];
  const float* wo_w = (const float*)d_in[10];
  const float* wo_b = (const float*)d_in[11];

  // ws layout (shorts)
  short* qb = (short*)d_ws;       // qb,kb,vb contiguous (Acat): 3*BSD
  short* wqb = qb + 3 * BSD;      // wq,wk,wv contiguous (Bcat): 3*DDn
  short* wob = wqb + 3 * DDn;     // DDn
  short* qh = wob + DDn;
  short* kh = qh + BSD;
  short* vhT = kh + BSD;
  short* concat = vhT + BSD;

  float* out0 = (float*)d_out;
  float* wts = out0 + BSD;  // [B,H,S,S] fp32

  cvtw_k<<<2048, 256, 0, stream>>>(wq_w, wk_w, wv_w, wo_w, wqb);
  cvt3_k<<<6144, 256, 0, stream>>>(q, k, v, qb);

  dim3 gproj(DDim / 128, (NB * SS) / 128, 3);  // (8, 32, 3)
  proj3_k<<<gproj, 256, 0, stream>>>(qb, wqb, wq_b, wk_b, wv_b, qh, kh, vhT);

  dim3 gattn(SS / 128, NB * NH);  // (16, 32)
  attn_k<<<gattn, 256, 0, stream>>>(qh, kh, vhT, mask, wts, concat);

  dim3 gout(DDim / 128, (NB * SS) / 128);  // (8, 32)
  outproj_k<<<gout, 256, 0, stream>>>(concat, wob, wo_b, out0);
}

// Round 8
// 315.233 us; speedup vs baseline: 1.1392x; 1.0533x over previous
//
#include <hip/hip_runtime.h>
#include <stdint.h>
#include <stddef.h>

static constexpr int NB = 2;       // batch
static constexpr int SS = 2048;    // seq
static constexpr int DDim = 1024;  // model dim
static constexpr int NH = 16;      // heads
static constexpr size_t BSD = (size_t)NB * SS * DDim;  // 4194304
static constexpr size_t DDn = (size_t)DDim * DDim;     // 1048576

typedef __attribute__((ext_vector_type(4))) float f32x4;
typedef __attribute__((ext_vector_type(8))) short bf16x8;
typedef __attribute__((ext_vector_type(4))) short bf16x4;

// exp2-folded constants: softmax uses exp2f(logit*SCL2 + mask*MSK2)
static constexpr float SCL2 = 0.125f * 1.4426950408889634f;
static constexpr float MSK2 = -1.4426950408889634e9f;

__device__ __forceinline__ short f2bf(float f) {
  union { float f; unsigned u; } v; v.f = f;
  unsigned r = v.u + 0x7FFFu + ((v.u >> 16) & 1u);
  return (short)(r >> 16);
}

__device__ __forceinline__ void gload_lds16(const void* src, void* dst) {
  __builtin_amdgcn_global_load_lds(
      (const __attribute__((address_space(1))) void*)src,
      (__attribute__((address_space(3))) void*)dst, 16, 0, 0);
}

// ---------------- fp32 -> bf16 convert: q,k,v + 4 weight mats, ONE launch ----------------
// Output region is contiguous in ws: [q|k|v] (3*BSD) then [wq|wk|wv|wo] (4*DDn).
__global__ void cvt_all_k(const float* __restrict__ q, const float* __restrict__ k,
                          const float* __restrict__ v, const float* __restrict__ w0,
                          const float* __restrict__ w1, const float* __restrict__ w2,
                          const float* __restrict__ w3, short* __restrict__ out) {
  int i = blockIdx.x * 256 + threadIdx.x;  // in [0, 3*BSD/8 + 4*DDn/8) = [0, 2097152)
  const float* src;
  int j;
  if (i < 1572864) {             // 3 * BSD/8, BSD/8 = 2^19
    int mat = i >> 19;
    src = mat == 0 ? q : mat == 1 ? k : v;
    j = i & 524287;
  } else {
    int t = i - 1572864;         // DDn/8 = 2^17
    int mat = t >> 17;
    src = mat == 0 ? w0 : mat == 1 ? w1 : mat == 2 ? w2 : w3;
    j = t & 131071;
  }
  const f32x4* p = (const f32x4*)src + (size_t)j * 2;
  f32x4 a = p[0], c = p[1];
  bf16x8 o;
  o[0] = f2bf(a[0]); o[1] = f2bf(a[1]); o[2] = f2bf(a[2]); o[3] = f2bf(a[3]);
  o[4] = f2bf(c[0]); o[5] = f2bf(c[1]); o[6] = f2bf(c[2]); o[7] = f2bf(c[3]);
  ((bf16x8*)out)[i] = o;
}

// ---------------- all-3 projections, one launch (R3/R5-proven dbuf GEMM body) ----------------
__global__ __launch_bounds__(256, 2) void proj3_k(
    const short* __restrict__ Acat, const short* __restrict__ Bcat,
    const float* __restrict__ bq, const float* __restrict__ bk, const float* __restrict__ bv,
    short* __restrict__ qh, short* __restrict__ kh, short* __restrict__ vhT) {
  __shared__ short la[2][4096], lb[2][4096];
  const int tid = threadIdx.x, wid = tid >> 6, lane = tid & 63;
  const int proj = blockIdx.z;
  const short* A = Acat + (size_t)proj * BSD;
  const short* Bm = Bcat + (size_t)proj * DDn;
  const float* bias = proj == 0 ? bq : proj == 1 ? bk : bv;
  const int bM = blockIdx.y * 128, bN = blockIdx.x * 128;
  const int ar = lane & 15, ak = (lane >> 4) * 8;
  const int srow = lane >> 2, scol = (lane & 3) * 8;
  const int wr = wid >> 1, wc = wid & 1;
  f32x4 acc[4][4];
#pragma unroll
  for (int m = 0; m < 4; ++m)
#pragma unroll
    for (int n = 0; n < 4; ++n) acc[m][n] = (f32x4){0.f, 0.f, 0.f, 0.f};

  auto stage = [&](int kt, int bb) {
    const int k0 = kt * 32;
#pragma unroll
    for (int c = 0; c < 2; ++c) {
      int chunk = c * 4 + wid;
      gload_lds16(A + (size_t)(bM + chunk * 16 + srow) * DDim + k0 + scol, &la[bb][chunk * 512]);
      gload_lds16(Bm + (size_t)(bN + chunk * 16 + srow) * DDim + k0 + scol, &lb[bb][chunk * 512]);
    }
  };

  stage(0, 0);
  asm volatile("s_waitcnt vmcnt(0)" ::: "memory");
  __syncthreads();
  for (int kt = 0; kt < 32; ++kt) {
    const int bb = kt & 1;
    if (kt < 31) stage(kt + 1, bb ^ 1);
    bf16x8 af[4], bfr[4];
#pragma unroll
    for (int m = 0; m < 4; ++m)
      af[m] = *(const bf16x8*)(&la[bb][(wr * 64 + m * 16 + ar) * 32 + ak]);
#pragma unroll
    for (int n = 0; n < 4; ++n)
      bfr[n] = *(const bf16x8*)(&lb[bb][(wc * 64 + n * 16 + ar) * 32 + ak]);
#pragma unroll
    for (int m = 0; m < 4; ++m)
#pragma unroll
      for (int n = 0; n < 4; ++n)
        acc[m][n] = __builtin_amdgcn_mfma_f32_16x16x32_bf16(af[m], bfr[n], acc[m][n], 0, 0, 0);
    asm volatile("s_waitcnt vmcnt(0)" ::: "memory");
    __syncthreads();
  }
#pragma unroll
  for (int m = 0; m < 4; ++m)
#pragma unroll
    for (int n = 0; n < 4; ++n)
#pragma unroll
      for (int r = 0; r < 4; ++r) {
        int gm = bM + wr * 64 + m * 16 + (lane >> 4) * 4 + r;
        int gn = bN + wc * 64 + n * 16 + (lane & 15);
        float val = acc[m][n][r] + bias[gn];
        int b = gm >> 11, s = gm & 2047, h = gn >> 6, d = gn & 63;
        if (proj == 2)
          vhT[(((size_t)b * NH + h) * 64 + d) * SS + s] = f2bf(val);
        else {
          short* o = proj == 0 ? qh : kh;
          o[(((size_t)b * NH + h) * SS + s) * 64 + d] = f2bf(val);
        }
      }
}

// ---------------- output projection (R3/R5-proven dbuf GEMM body, fp32 out) ----------------
__global__ __launch_bounds__(256, 2) void outproj_k(
    const short* __restrict__ A, const short* __restrict__ Bm,
    const float* __restrict__ bias, float* __restrict__ outp) {
  __shared__ short la[2][4096], lb[2][4096];
  const int tid = threadIdx.x, wid = tid >> 6, lane = tid & 63;
  const int bM = blockIdx.y * 128, bN = blockIdx.x * 128;
  const int ar = lane & 15, ak = (lane >> 4) * 8;
  const int srow = lane >> 2, scol = (lane & 3) * 8;
  const int wr = wid >> 1, wc = wid & 1;
  f32x4 acc[4][4];
#pragma unroll
  for (int m = 0; m < 4; ++m)
#pragma unroll
    for (int n = 0; n < 4; ++n) acc[m][n] = (f32x4){0.f, 0.f, 0.f, 0.f};

  auto stage = [&](int kt, int bb) {
    const int k0 = kt * 32;
#pragma unroll
    for (int c = 0; c < 2; ++c) {
      int chunk = c * 4 + wid;
      gload_lds16(A + (size_t)(bM + chunk * 16 + srow) * DDim + k0 + scol, &la[bb][chunk * 512]);
      gload_lds16(Bm + (size_t)(bN + chunk * 16 + srow) * DDim + k0 + scol, &lb[bb][chunk * 512]);
    }
  };

  stage(0, 0);
  asm volatile("s_waitcnt vmcnt(0)" ::: "memory");
  __syncthreads();
  for (int kt = 0; kt < 32; ++kt) {
    const int bb = kt & 1;
    if (kt < 31) stage(kt + 1, bb ^ 1);
    bf16x8 af[4], bfr[4];
#pragma unroll
    for (int m = 0; m < 4; ++m)
      af[m] = *(const bf16x8*)(&la[bb][(wr * 64 + m * 16 + ar) * 32 + ak]);
#pragma unroll
    for (int n = 0; n < 4; ++n)
      bfr[n] = *(const bf16x8*)(&lb[bb][(wc * 64 + n * 16 + ar) * 32 + ak]);
#pragma unroll
    for (int m = 0; m < 4; ++m)
#pragma unroll
      for (int n = 0; n < 4; ++n)
        acc[m][n] = __builtin_amdgcn_mfma_f32_16x16x32_bf16(af[m], bfr[n], acc[m][n], 0, 0, 0);
    asm volatile("s_waitcnt vmcnt(0)" ::: "memory");
    __syncthreads();
  }
#pragma unroll
  for (int m = 0; m < 4; ++m)
#pragma unroll
    for (int n = 0; n < 4; ++n)
#pragma unroll
      for (int r = 0; r < 4; ++r) {
        int gm = bM + wr * 64 + m * 16 + (lane >> 4) * 4 + r;
        int gn = bN + wc * 64 + n * 16 + (lane & 15);
        outp[(size_t)gm * DDim + gn] = acc[m][n][r] + bias[gn];
      }
}

// ---------------- fused attention (R5-proven skeleton, swapped-QK^T, plain stores) ------------
// One block = one (b,h) x one 128-row q-tile, 256 threads, ~73KB LDS -> 2 blocks/CU.
// QK^T computed as mfma(K_frag, Q_frag): each lane's f32x4 holds 4 consecutive k for
// one q row -> W-stores are dwordx4 (plain, through L2), P LDS writes are b64,
// row-reduce is 2 shuffles. Staging/barriers identical to R5.
__global__ __launch_bounds__(256, 2) void attn_k(
    const short* __restrict__ qh, const short* __restrict__ kh,
    const short* __restrict__ vhT, const float* __restrict__ mask,
    float* __restrict__ wout, short* __restrict__ concat) {
  __shared__ short lP[128 * 128];  // Q staging, then P tile (bf16, swizzled)
  __shared__ short lK[128 * 64];   // K tile (swizzled)
  __shared__ short lV[64 * 128];   // V^T tile (swizzled)
  __shared__ float lmask[2048];
  __shared__ float lrs[2][128];
  const int tid = threadIdx.x, wid = tid >> 6, lane = tid & 63;
  const int wr = wid >> 1, wc = wid & 1;
  const int bh = blockIdx.y, b = bh >> 4, h = bh & 15;
  const int bM = blockIdx.x * 128;
  const short* Qb = qh + (size_t)bh * SS * 64 + (size_t)bM * 64;
  const short* Kb = kh + (size_t)bh * SS * 64;
  const short* Vb = vhT + (size_t)bh * 64 * SS;
  float* Wb = wout + (size_t)bh * SS * SS;

#pragma unroll
  for (int i = 0; i < 8; ++i)
    lmask[tid + i * 256] = mask[b * SS + tid + i * 256] * MSK2;

  // stage Q tile [128][64] swizzled into lP
#pragma unroll
  for (int c = 0; c < 4; ++c) {
    int ob = c * 4096 + tid * 16;
    int row = ob >> 7, inrow = ob & 127;
    gload_lds16(Qb + row * 64 + ((inrow ^ ((row & 7) << 4)) >> 1), (char*)lP + ob);
  }
  asm volatile("s_waitcnt vmcnt(0)" ::: "memory");
  __syncthreads();
  bf16x8 af[4][2];  // Q fragments: rows wr*64+nq*16+(lane&15)
#pragma unroll
  for (int m = 0; m < 4; ++m)
#pragma unroll
    for (int kk = 0; kk < 2; ++kk) {
      int row = wr * 64 + m * 16 + (lane & 15);
      int kb = (kk * 32 + (lane >> 4) * 8) * 2;
      af[m][kk] = *(const bf16x8*)((const char*)lP + row * 128 + (kb ^ ((row & 7) << 4)));
    }

  // ---- sweep 1: row sums of exp2(logit*SCL2 + maskterm) ----
  float ps[4];  // per nq (q = wr*64 + nq*16 + (lane&15))
#pragma unroll
  for (int n = 0; n < 4; ++n) ps[n] = 0.f;

  for (int kt = 0; kt < 16; ++kt) {
    __syncthreads();
#pragma unroll
    for (int c = 0; c < 4; ++c) {
      int ob = c * 4096 + tid * 16;
      int row = ob >> 7, inrow = ob & 127;
      gload_lds16(Kb + (size_t)(kt * 128 + row) * 64 + ((inrow ^ ((row & 7) << 4)) >> 1),
                  (char*)lK + ob);
    }
    asm volatile("s_waitcnt vmcnt(0)" ::: "memory");
    __syncthreads();
    bf16x8 bfr[4][2];  // K fragments: rows wc*64+mk*16+(lane&15)
#pragma unroll
    for (int mk = 0; mk < 4; ++mk)
#pragma unroll
      for (int kk = 0; kk < 2; ++kk) {
        int row = wc * 64 + mk * 16 + (lane & 15);
        int kb = (kk * 32 + (lane >> 4) * 8) * 2;
        bfr[mk][kk] = *(const bf16x8*)((const char*)lK + row * 128 + (kb ^ ((row & 7) << 4)));
      }
#pragma unroll
    for (int mk = 0; mk < 4; ++mk) {
      f32x4 mv4 = *(const f32x4*)&lmask[kt * 128 + wc * 64 + mk * 16 + (lane >> 4) * 4];
#pragma unroll
      for (int nq = 0; nq < 4; ++nq) {
        f32x4 a = (f32x4){0.f, 0.f, 0.f, 0.f};
        a = __builtin_amdgcn_mfma_f32_16x16x32_bf16(bfr[mk][0], af[nq][0], a, 0, 0, 0);
        a = __builtin_amdgcn_mfma_f32_16x16x32_bf16(bfr[mk][1], af[nq][1], a, 0, 0, 0);
#pragma unroll
        for (int r = 0; r < 4; ++r) ps[nq] += exp2f(a[r] * SCL2 + mv4[r]);
      }
    }
  }
  // reduce across the 4 lane-groups (lane>>4) holding one q's k-chunks
#pragma unroll
  for (int n = 0; n < 4; ++n) {
    float s = ps[n];
    s += __shfl_xor(s, 16, 64);
    s += __shfl_xor(s, 32, 64);
    ps[n] = s;
  }
  if (lane < 16) {
#pragma unroll
    for (int n = 0; n < 4; ++n) lrs[wc][wr * 64 + n * 16 + lane] = ps[n];
  }
  __syncthreads();
  float inv[4];
#pragma unroll
  for (int n = 0; n < 4; ++n) {
    int row = wr * 64 + n * 16 + (lane & 15);
    inv[n] = 1.f / (lrs[0][row] + lrs[1][row]);
  }

  // ---- sweep 2: recompute logits, write weights (x4), PV accumulate ----
  f32x4 pacc[4][2];
#pragma unroll
  for (int m = 0; m < 4; ++m)
#pragma unroll
    for (int n = 0; n < 2; ++n) pacc[m][n] = (f32x4){0.f, 0.f, 0.f, 0.f};

  for (int kt = 0; kt < 16; ++kt) {
    __syncthreads();
#pragma unroll
    for (int c = 0; c < 4; ++c) {
      int ob = c * 4096 + tid * 16;
      int row = ob >> 7, inrow = ob & 127;
      gload_lds16(Kb + (size_t)(kt * 128 + row) * 64 + ((inrow ^ ((row & 7) << 4)) >> 1),
                  (char*)lK + ob);
    }
#pragma unroll
    for (int c = 0; c < 4; ++c) {
      int ob = c * 4096 + tid * 16;
      int row = ob >> 8, inrow = ob & 255;
      gload_lds16(Vb + (size_t)row * SS + kt * 128 + ((inrow ^ ((row & 7) << 4)) >> 1),
                  (char*)lV + ob);
    }
    asm volatile("s_waitcnt vmcnt(0)" ::: "memory");
    __syncthreads();
    bf16x8 bfr[4][2];
#pragma unroll
    for (int mk = 0; mk < 4; ++mk)
#pragma unroll
      for (int kk = 0; kk < 2; ++kk) {
        int row = wc * 64 + mk * 16 + (lane & 15);
        int kb = (kk * 32 + (lane >> 4) * 8) * 2;
        bfr[mk][kk] = *(const bf16x8*)((const char*)lK + row * 128 + (kb ^ ((row & 7) << 4)));
      }
#pragma unroll
    for (int mk = 0; mk < 4; ++mk) {
      const int klocal = wc * 64 + mk * 16 + (lane >> 4) * 4;
      f32x4 mv4 = *(const f32x4*)&lmask[kt * 128 + klocal];
#pragma unroll
      for (int nq = 0; nq < 4; ++nq) {
        f32x4 a = (f32x4){0.f, 0.f, 0.f, 0.f};
        a = __builtin_amdgcn_mfma_f32_16x16x32_bf16(bfr[mk][0], af[nq][0], a, 0, 0, 0);
        a = __builtin_amdgcn_mfma_f32_16x16x32_bf16(bfr[mk][1], af[nq][1], a, 0, 0, 0);
        const int qrow = wr * 64 + nq * 16 + (lane & 15);
        f32x4 w4;
#pragma unroll
        for (int r = 0; r < 4; ++r) w4[r] = exp2f(a[r] * SCL2 + mv4[r]) * inv[nq];
        *(f32x4*)&Wb[(size_t)(bM + qrow) * SS + kt * 128 + klocal] = w4;
        bf16x4 p4;
        p4[0] = f2bf(w4[0]); p4[1] = f2bf(w4[1]); p4[2] = f2bf(w4[2]); p4[3] = f2bf(w4[3]);
        *(bf16x4*)((char*)lP + qrow * 256 + ((klocal * 2) ^ ((qrow & 7) << 4))) = p4;
      }
    }
    __syncthreads();  // lP ready
    // PV: out[q][d] += P[q][k] * V^T[d][k]
#pragma unroll
    for (int kk = 0; kk < 4; ++kk) {
      bf16x8 pa[4], bv[2];
      int kb = (kk * 32 + (lane >> 4) * 8) * 2;
#pragma unroll
      for (int m = 0; m < 4; ++m) {
        int row = wr * 64 + m * 16 + (lane & 15);
        pa[m] = *(const bf16x8*)((const char*)lP + row * 256 + (kb ^ ((row & 7) << 4)));
      }
#pragma unroll
      for (int n = 0; n < 2; ++n) {
        int d = wc * 32 + n * 16 + (lane & 15);
        bv[n] = *(const bf16x8*)((const char*)lV + d * 256 + (kb ^ ((d & 7) << 4)));
      }
#pragma unroll
      for (int m = 0; m < 4; ++m)
#pragma unroll
        for (int n = 0; n < 2; ++n)
          pacc[m][n] = __builtin_amdgcn_mfma_f32_16x16x32_bf16(pa[m], bv[n], pacc[m][n], 0, 0, 0);
    }
  }
  // epilogue: attn (concat layout) bf16
#pragma unroll
  for (int m = 0; m < 4; ++m)
#pragma unroll
    for (int n = 0; n < 2; ++n)
#pragma unroll
      for (int r = 0; r < 4; ++r) {
        int s = bM + wr * 64 + m * 16 + (lane >> 4) * 4 + r;
        int d = wc * 32 + n * 16 + (lane & 15);
        concat[((size_t)(b * SS + s)) * DDim + h * 64 + d] = f2bf(pacc[m][n][r]);
      }
}

extern "C" void kernel_launch(void* const* d_in, const int* in_sizes, int n_in,
                              void* d_out, int out_size, void* d_ws, size_t ws_size,
                              hipStream_t stream) {
  const float* q = (const float*)d_in[0];
  const float* k = (const float*)d_in[1];
  const float* v = (const float*)d_in[2];
  const float* mask = (const float*)d_in[3];
  const float* wq_w = (const float*)d_in[4];
  const float* wq_b = (const float*)d_in[5];
  const float* wk_w = (const float*)d_in[6];
  const float* wk_b = (const float*)d_in[7];
  const float* wv_w = (const float*)d_in[8];
  const float* wv_b = (const float*)d_in[9];
  const float* wo_w = (const float*)d_in[10];
  const float* wo_b = (const float*)d_in[11];

  // ws layout (shorts): one contiguous cvt output region [q|k|v|wq|wk|wv|wo]
  short* qb = (short*)d_ws;       // 3*BSD
  short* wqb = qb + 3 * BSD;      // 3*DDn (wq,wk,wv = Bcat)
  short* wob = wqb + 3 * DDn;     // DDn
  short* qh = wob + DDn;
  short* kh = qh + BSD;
  short* vhT = kh + BSD;
  short* concat = vhT + BSD;

  float* out0 = (float*)d_out;
  float* wts = out0 + BSD;  // [B,H,S,S] fp32

  cvt_all_k<<<8192, 256, 0, stream>>>(q, k, v, wq_w, wk_w, wv_w, wo_w, qb);

  dim3 gproj(DDim / 128, (NB * SS) / 128, 3);  // (8, 32, 3)
  proj3_k<<<gproj, 256, 0, stream>>>(qb, wqb, wq_b, wk_b, wv_b, qh, kh, vhT);

  dim3 gattn(SS / 128, NB * NH);  // (16, 32)
  attn_k<<<gattn, 256, 0, stream>>>(qh, kh, vhT, mask, wts, concat);

  dim3 gout(DDim / 128, (NB * SS) / 128);  // (8, 32)
  outproj_k<<<gout, 256, 0, stream>>>(concat, wob, wo_b, out0);
}